// Round 1
// 84.200 us; speedup vs baseline: 1.0474x; 1.0474x over previous
//
#include <hip/hip_runtime.h>
#include <hip/hip_bf16.h>

typedef __bf16 bf16x8 __attribute__((ext_vector_type(8)));
typedef float  f32x4  __attribute__((ext_vector_type(4)));
typedef float  f32x16 __attribute__((ext_vector_type(16)));

constexpr int Bn = 8192, Dn = 64, On = 256;

// async global->LDS DMA (dest = wave-uniform base + lane*16)
#define GLD16(g, l) __builtin_amdgcn_global_load_lds( \
    (const __attribute__((address_space(1))) void*)(g), \
    (__attribute__((address_space(3))) void*)(l), 16, 0, 0)

// ---- prep ----
// bTf[o][f][lane][8] : fragment-major bf16 A-image. k_main loads it straight to
// VGPRs with coalesced dwordx4 (no LDS roundtrip => no swizzle needed).
//   af[f][j] for lane l must be betas[o][d][e], e=(f>>2)*32+(l&31),
//   d=((f&3)*2+(l>>5))*8+j   (f = et*4+k of the old layout)
// ncpk[o][64] = -c_proj packed in 32x32 C-register order (unchanged).
__global__ void k_prep(const float* __restrict__ betas, const float* __restrict__ centers,
                       __bf16* __restrict__ bTf, float* __restrict__ ncpk) {
    __shared__ float s[64 * 65];                        // +1 pad transpose buffer
    const int o = blockIdx.x, tid = threadIdx.x;
    const float* bo = betas + (size_t)o * 4096;         // betas[o][d][e]
    for (int j = tid; j < 1024; j += 256) {
        int d = j >> 4, e4 = (j & 15) * 4;
        float4 v = ((const float4*)bo)[j];
        s[d * 65 + e4 + 0] = v.x; s[d * 65 + e4 + 1] = v.y;
        s[d * 65 + e4 + 2] = v.z; s[d * 65 + e4 + 3] = v.w;
    }
    __syncthreads();
    for (int j = tid; j < 4096; j += 256) {             // coalesced bf16 writes
        int f = j >> 9, l = (j >> 3) & 63, jj = j & 7;
        int e = ((f >> 2) << 5) + (l & 31);
        int d = (((f & 3) << 1) + (l >> 5)) * 8 + jj;
        bTf[(size_t)o * 4096 + j] = (__bf16)s[d * 65 + e];
    }
    // -cproj packed: row = 32*et + 4*l5 + (reg&3) + 8*(reg>>2)
    if (tid < 64) {
        int et = tid >> 5, rem = tid & 31, l5 = rem >> 4, reg = rem & 15;
        int row = et * 32 + l5 * 4 + (reg & 3) + ((reg >> 2) << 3);
        float acc = 0.f;
        for (int d = 0; d < 64; ++d) acc += s[d * 65 + row] * centers[o * 64 + d];
        ncpk[o * 64 + tid] = -acc;
    }
}

// ---- main ----
template <int OI>
__device__ __forceinline__ void ldA(const __bf16* __restrict__ gA, bf16x8 (&af)[8]) {
#pragma unroll
    for (int f = 0; f < 8; ++f)
        af[f] = *(const bf16x8*)(gA + OI * 4096 + f * 512);
}

template <int OI>
__device__ __forceinline__ void step(const float* __restrict__ cpw, const bf16x8 (&af)[8],
                                     const bf16x8 (&xf)[4][4], int l5,
                                     f32x4 (&eA)[2], f32x4 (&eB)[2]) {
    f32x4 qv[4] = {{0.f,0.f,0.f,0.f},{0.f,0.f,0.f,0.f},{0.f,0.f,0.f,0.f},{0.f,0.f,0.f,0.f}};
#pragma unroll
    for (int et = 0; et < 2; ++et) {
        f32x16 cpv;                                     // C-init = -cp, broadcast ds_reads
#pragma unroll
        for (int r4 = 0; r4 < 4; ++r4)
            ((f32x4*)&cpv)[r4] = *(const f32x4*)(cpw + OI * 64 + et * 32 + l5 * 16 + r4 * 4);
#pragma unroll
        for (int bt = 0; bt < 4; ++bt) {
            f32x16 acc = __builtin_amdgcn_mfma_f32_32x32x16_bf16(af[et*4+0], xf[bt][0], cpv, 0, 0, 0);
            acc = __builtin_amdgcn_mfma_f32_32x32x16_bf16(af[et*4+1], xf[bt][1], acc, 0, 0, 0);
            acc = __builtin_amdgcn_mfma_f32_32x32x16_bf16(af[et*4+2], xf[bt][2], acc, 0, 0, 0);
            acc = __builtin_amdgcn_mfma_f32_32x32x16_bf16(af[et*4+3], xf[bt][3], acc, 0, 0, 0);
#pragma unroll
            for (int j = 0; j < 16; ++j)                // qv += (y-cp)^2
                qv[bt][j & 3] = fmaf(acc[j], acc[j], qv[bt][j & 3]);
        }
    }
    float q[4];
#pragma unroll
    for (int bt = 0; bt < 4; ++bt) {
        float qs = (qv[bt][0] + qv[bt][1]) + (qv[bt][2] + qv[bt][3]);
        qs += __shfl_xor(qs, 32, 64);
        q[bt] = qs;
    }
    float qA = l5 ? q[2] : q[0], qB = l5 ? q[3] : q[1];
    eA[OI >> 2][OI & 3] = __expf(-qA);                  // static idx (OI is template const)
    eB[OI >> 2][OI & 3] = __expf(-qB);
}

__global__ void __launch_bounds__(256)
__attribute__((amdgpu_waves_per_eu(2, 2)))
k_main(const float* __restrict__ x, const __bf16* __restrict__ bTf,
       const float* __restrict__ ncpk, float* __restrict__ out) {
    __shared__ __align__(16) __bf16 sX[128 * 64];       // 16 KB, xor-swizzled
    __shared__ __align__(16) float  sCp[4][512];        // 2 KB per wave (8 o's of -cp)

    const int tid = threadIdx.x, wq = tid >> 6, lane = tid & 63;
    const int l31 = lane & 31, l5 = lane >> 5;
    const int bbase = blockIdx.x * 128;
    const int o0 = blockIdx.y * 32 + wq * 8;

    // all 8 o's of -cp for this wave -> wave-private LDS (drained by the barrier)
    GLD16(ncpk + o0 * 64 + lane * 4, &sCp[wq][0]);
    GLD16(ncpk + o0 * 64 + 256 + lane * 4, &sCp[wq][256]);

    // A prologue prefetch (direct global->VGPR, overlaps x-staging)
    const __bf16* gA = bTf + (size_t)o0 * 4096 + (size_t)lane * 8;
    bf16x8 a0[8], a1[8];
    ldA<0>(gA, a0);

    // stage x fp32 -> bf16, chunk (rb, c) at slot c^(rb&7)
#pragma unroll
    for (int i = 0; i < 4; ++i) {
        int id = i * 256 + tid, rb = id >> 3, c = id & 7;
        const float* xp = x + (size_t)(bbase + rb) * 64 + c * 8;
        float4 v0 = *(const float4*)xp, v1 = *(const float4*)(xp + 4);
        bf16x8 f;
        f[0] = (__bf16)v0.x; f[1] = (__bf16)v0.y; f[2] = (__bf16)v0.z; f[3] = (__bf16)v0.w;
        f[4] = (__bf16)v1.x; f[5] = (__bf16)v1.y; f[6] = (__bf16)v1.z; f[7] = (__bf16)v1.w;
        *(bf16x8*)(sX + rb * 64 + ((c ^ (rb & 7)) << 3)) = f;
    }
    __syncthreads();                                    // the only barrier

    // resident x-fragments: B-operand, n = l31, k = l5*8+j
    bf16x8 xf[4][4];
#pragma unroll
    for (int bt = 0; bt < 4; ++bt)
#pragma unroll
        for (int k = 0; k < 4; ++k) {
            int row = bt * 32 + l31, c = k * 2 + l5;
            xf[bt][k] = *(const bf16x8*)(sX + row * 64 + ((c ^ (row & 7)) << 3));
        }

    const float* cpw = &sCp[wq][0];
    f32x4 eA[2], eB[2];

    // 1-deep register ping-pong: prefetch o+1 while computing o. No in-loop
    // barriers / vmcnt(0) drains; compiler emits counted vmcnt on first use.
    // sched_barrier after each step = WAR fence only (stops unroll-wide hoist).
    ldA<1>(gA, a1); step<0>(cpw, a0, xf, l5, eA, eB);
    __builtin_amdgcn_sched_barrier(0);
    ldA<2>(gA, a0); step<1>(cpw, a1, xf, l5, eA, eB);
    __builtin_amdgcn_sched_barrier(0);
    ldA<3>(gA, a1); step<2>(cpw, a0, xf, l5, eA, eB);
    __builtin_amdgcn_sched_barrier(0);
    ldA<4>(gA, a0); step<3>(cpw, a1, xf, l5, eA, eB);
    __builtin_amdgcn_sched_barrier(0);
    ldA<5>(gA, a1); step<4>(cpw, a0, xf, l5, eA, eB);
    __builtin_amdgcn_sched_barrier(0);
    ldA<6>(gA, a0); step<5>(cpw, a1, xf, l5, eA, eB);
    __builtin_amdgcn_sched_barrier(0);
    ldA<7>(gA, a1); step<6>(cpw, a0, xf, l5, eA, eB);
    __builtin_amdgcn_sched_barrier(0);
    step<7>(cpw, a1, xf, l5, eA, eB);

    // batched coalesced-ish stores: 2 rows x 32B contiguous per lane
    const int bA = bbase + l5 * 64 + l31;
    float* op = out + (size_t)bA * 256 + o0;
    *(f32x4*)(op)                = eA[0];
    *(f32x4*)(op + 4)            = eA[1];
    *(f32x4*)(op + 32 * 256)     = eB[0];
    *(f32x4*)(op + 32 * 256 + 4) = eB[1];
}

extern "C" void kernel_launch(void* const* d_in, const int* in_sizes, int n_in,
                              void* d_out, int out_size, void* d_ws, size_t ws_size,
                              hipStream_t stream) {
    const float* x       = (const float*)d_in[0];   // [8192,64]
    const float* centers = (const float*)d_in[1];   // [256,1,64]
    const float* betas   = (const float*)d_in[2];   // [256,64,64]
    float* out = (float*)d_out;                     // [8192,256] fp32

    char* ws = (char*)d_ws;
    __bf16* bTf  = (__bf16*)ws;                     // 2 MB (fragment-major A-images)
    float*  ncpk = (float*)(ws + 2 * (1 << 20));    // 64 KB (packed -cproj)

    k_prep<<<dim3(On),                dim3(256), 0, stream>>>(betas, centers, bTf, ncpk);
    k_main<<<dim3(Bn / 128, On / 32), dim3(256), 0, stream>>>(x, bTf, ncpk, out);
}